// Round 4
// baseline (342.054 us; speedup 1.0000x reference)
//
#include <hip/hip_runtime.h>
#include <hip/hip_bf16.h>

// out[i] = sum_j bit(x[i,j]) * 2^j,  bit = (sign(x)+1)/2 in {0, 0.5, 1}.
// N=4M rows, D=16 fp32. Memory-bound streaming: 256 MB read + 16 MB write
// -> ~42 us kernel floor at 6.5 TB/s. dur_us additionally carries ~240 us of
// harness restore/poison (1 GB ws fill ~155 us + 256 MB input restore ~80 us),
// visible directly in the rocprof top-5.
//
// R4: 8 independent chunks/thread (MLP=8), loads made unconditional via index
// clamp (guard only the store), nt stores. Per-instruction coalescing stays
// perfect: lane i loads x4[chunk_base + i], 16 B/lane = 1 KB/wave-load.
// All weights are powers of two -> exact fp32 math, same numerics as the
// passing R1-R3 kernels.

typedef float f32x4 __attribute__((ext_vector_type(4)));

__global__ __launch_bounds__(256) void bcd_reverse_kernel(
    const f32x4* __restrict__ x4, float* __restrict__ out, int n4) {
  const int tid = threadIdx.x;
  const int base = blockIdx.x * 2048 + tid;  // 256 thr * 8 chunks

  // 8 independent loads, all in flight before first use. Clamp keeps the
  // tail block in-bounds without a 128-bit select on the load path.
  f32x4 f[8];
#pragma unroll
  for (int c = 0; c < 8; ++c) {
    int idx = min(base + c * 256, n4 - 1);
    f[c] = x4[idx];
  }

  const int q = tid & 3;                     // quarter of the row
  const float w0 = (float)(1u << (4 * q));   // 2^(4q): 1, 16, 256, 4096

#pragma unroll
  for (int c = 0; c < 8; ++c) {
    // jnp.sign semantics: bit = 1 for >0, 0 for <0, 0.5 for ==0.
    float b0 = (f[c].x > 0.0f) ? 1.0f : ((f[c].x < 0.0f) ? 0.0f : 0.5f);
    float b1 = (f[c].y > 0.0f) ? 1.0f : ((f[c].y < 0.0f) ? 0.0f : 0.5f);
    float b2 = (f[c].z > 0.0f) ? 1.0f : ((f[c].z < 0.0f) ? 0.0f : 0.5f);
    float b3 = (f[c].w > 0.0f) ? 1.0f : ((f[c].w < 0.0f) ? 0.0f : 0.5f);

    // (b0 + 2 b1 + 4 b2 + 8 b3) * 2^(4q): power-of-two scaling is exact.
    float partial = w0 * fmaf(8.0f, b3, fmaf(4.0f, b2, fmaf(2.0f, b1, b0)));

    // quad reduction across lanes {4r..4r+3}
    partial += __shfl_xor(partial, 1);
    partial += __shfl_xor(partial, 2);

    int idx = base + c * 256;
    if (q == 0 && idx < n4)
      __builtin_nontemporal_store(partial, &out[idx >> 2]);
  }
}

extern "C" void kernel_launch(void* const* d_in, const int* in_sizes, int n_in,
                              void* d_out, int out_size, void* d_ws, size_t ws_size,
                              hipStream_t stream) {
  const f32x4* x4 = (const f32x4*)d_in[0];
  float* out = (float*)d_out;
  const int n4 = in_sizes[0] / 4;  // 16,000,000 float4s

  const int block = 256;
  const int per_block = block * 8;                     // 2048 float4s/block
  const int grid = (n4 + per_block - 1) / per_block;   // 7813 blocks
  bcd_reverse_kernel<<<grid, block, 0, stream>>>(x4, out, n4);
}

// Round 5
// 317.888 us; speedup vs baseline: 1.0760x; 1.0760x over previous
//
#include <hip/hip_runtime.h>
#include <hip/hip_bf16.h>

// out[i] = sum_j bit(x[i,j]) * 2^j,  bit = (sign(x)+1)/2 in {0, 0.5, 1}.
// N=4M rows, D=16 fp32. Memory-bound streaming: 256 MB read + 16 MB write
// -> ~42 us kernel floor at ~6.6 TB/s. dur_us additionally carries ~240 us
// of harness restore/poison (1 GB ws fill ~154 us + 256 MB input restore
// ~80 us), visible directly in the rocprof top-5.
//
// R4 lesson: MLP=8 regressed (+21 us) — request-rate was already saturated
// at MLP=4; extra outstanding loads only lengthen the vmcnt drain.
// R5 = R3 (best-known: MLP=4, nt load/store) + clamp-indexed loads (drops
// the 128-bit cndmask select chains; bounds guard only on the store).
// All weights are powers of two -> exact fp32 math, same numerics as all
// passing rounds.

typedef float f32x4 __attribute__((ext_vector_type(4)));

__global__ __launch_bounds__(256) void bcd_reverse_kernel(
    const f32x4* __restrict__ x4, float* __restrict__ out, int n4) {
  const int tid = threadIdx.x;
  const int base = blockIdx.x * 1024 + tid;  // 256 thr * 4 chunks

  // 4 independent loads in flight before first use; clamp keeps the tail
  // block in-bounds without a select on the loaded data.
  f32x4 f[4];
#pragma unroll
  for (int c = 0; c < 4; ++c) {
    int idx = min(base + c * 256, n4 - 1);
    f[c] = __builtin_nontemporal_load(&x4[idx]);
  }

  const int q = tid & 3;                     // quarter of the row
  const float w0 = (float)(1u << (4 * q));   // 2^(4q): 1, 16, 256, 4096

#pragma unroll
  for (int c = 0; c < 4; ++c) {
    // jnp.sign semantics: bit = 1 for >0, 0 for <0, 0.5 for ==0.
    float b0 = (f[c].x > 0.0f) ? 1.0f : ((f[c].x < 0.0f) ? 0.0f : 0.5f);
    float b1 = (f[c].y > 0.0f) ? 1.0f : ((f[c].y < 0.0f) ? 0.0f : 0.5f);
    float b2 = (f[c].z > 0.0f) ? 1.0f : ((f[c].z < 0.0f) ? 0.0f : 0.5f);
    float b3 = (f[c].w > 0.0f) ? 1.0f : ((f[c].w < 0.0f) ? 0.0f : 0.5f);

    // (b0 + 2 b1 + 4 b2 + 8 b3) * 2^(4q): power-of-two scaling is exact.
    float partial = w0 * fmaf(8.0f, b3, fmaf(4.0f, b2, fmaf(2.0f, b1, b0)));

    // quad reduction across lanes {4r..4r+3}
    partial += __shfl_xor(partial, 1);
    partial += __shfl_xor(partial, 2);

    int idx = base + c * 256;
    if (q == 0 && idx < n4)
      __builtin_nontemporal_store(partial, &out[idx >> 2]);
  }
}

extern "C" void kernel_launch(void* const* d_in, const int* in_sizes, int n_in,
                              void* d_out, int out_size, void* d_ws, size_t ws_size,
                              hipStream_t stream) {
  const f32x4* x4 = (const f32x4*)d_in[0];
  float* out = (float*)d_out;
  const int n4 = in_sizes[0] / 4;  // 16,000,000 float4s

  const int block = 256;
  const int per_block = block * 4;                     // 1024 float4s/block
  const int grid = (n4 + per_block - 1) / per_block;   // 15,625 blocks
  bcd_reverse_kernel<<<grid, block, 0, stream>>>(x4, out, n4);
}